// Round 1
// 517.489 us; speedup vs baseline: 1.1758x; 1.1758x over previous
//
#include <hip/hip_runtime.h>
#include <hip/hip_bf16.h>
#include <stdint.h>

// Problem dims (fixed by reference): x (4,2048,4096) f32, W (4096,4096) f32,
// bias (4096) f32, sparsity_scale (4096) f32. Tokens T = 8192.
#define T_TOK 8192
#define K_DIM 4096
#define N_DIM 4096
#define NT 64            // K_DIM / 64  (K-tiles of BK=64)

typedef short bf16x8 __attribute__((ext_vector_type(8)));
typedef float f32x4  __attribute__((ext_vector_type(4)));
typedef __attribute__((address_space(3))) char* ldsptr;

// RTNE f32 -> bf16 (bit manipulation; matches numpy/jax casts for finite vals)
__device__ __forceinline__ unsigned short f2bf(float f) {
    uint32_t u = __float_as_uint(f);
    u += 0x7FFFu + ((u >> 16) & 1u);
    return (unsigned short)(u >> 16);
}

// async global->LDS, 16B per lane. LDS dest must be wave-uniform base + lane*16.
__device__ __forceinline__ void gl16(const unsigned short* g, ldsptr l) {
    __builtin_amdgcn_global_load_lds(
        (const __attribute__((address_space(1))) void*)g,
        (__attribute__((address_space(3))) void*)l, 16, 0, 0);
}

// ---------------- kernel 0: W f32 -> bf16 ----------------
__global__ __launch_bounds__(256) void wconv_kernel(const float* __restrict__ w,
                                                    unsigned short* __restrict__ wb) {
    int i = (blockIdx.x * 256 + threadIdx.x) * 4;   // 4 floats per thread
    float4 v = *(const float4*)(w + i);
    ushort4 o;
    o.x = f2bf(v.x); o.y = f2bf(v.y); o.z = f2bf(v.z); o.w = f2bf(v.w);
    *(ushort4*)(wb + i) = o;
}

// ------- kernel 1: 2:4 sparsify + per-token absmax quant -> qi (bf16 ints), s -------
// one block (256 thr) per token row; each thread owns 4 groups of 4 consecutive cols
__global__ __launch_bounds__(256) void sparsequant_kernel(
        const float* __restrict__ x, const float* __restrict__ ss,
        unsigned short* __restrict__ qi, float* __restrict__ scales) {
    const int row = blockIdx.x;
    const int t = threadIdx.x;
    const float* xr = x + (size_t)row * K_DIM;

    float xs[16];
    float amax = 0.f;
#pragma unroll
    for (int j = 0; j < 4; ++j) {
        int g = t + 256 * j;                     // group index 0..1023
        float4 v  = ((const float4*)xr)[g];
        float4 sv = ((const float4*)ss)[g];
        float e[4] = { v.x, v.y, v.z, v.w };
        float m[4] = { fabsf(v.x) * sv.x, fabsf(v.y) * sv.y,
                       fabsf(v.z) * sv.z, fabsf(v.w) * sv.w };
#pragma unroll
        for (int a = 0; a < 4; ++a) {
            int cnt = 0;
#pragma unroll
            for (int b = 0; b < 4; ++b) {
                if (b == a) continue;
                // strict-order key (metric, index): matches stable top_k of smallest
                bool less = (m[b] < m[a]) || (m[b] == m[a] && b < a);
                cnt += less ? 1 : 0;
            }
            float kept = (cnt >= 2) ? e[a] : 0.f;   // zero the 2 smallest
            xs[j * 4 + a] = kept;
            amax = fmaxf(amax, fabsf(kept));
        }
    }
    // block max over 256 threads
#pragma unroll
    for (int off = 32; off >= 1; off >>= 1)
        amax = fmaxf(amax, __shfl_xor(amax, off, 64));
    __shared__ float wm[4];
    int wave = t >> 6, lane = t & 63;
    if (lane == 0) wm[wave] = amax;
    __syncthreads();
    amax = fmaxf(fmaxf(wm[0], wm[1]), fmaxf(wm[2], wm[3]));

    float s = fmaxf(amax, 1e-5f) / 127.0f;   // same f32 ops as reference
    if (t == 0) scales[row] = s;

    unsigned short* qr = qi + (size_t)row * K_DIM;
#pragma unroll
    for (int j = 0; j < 4; ++j) {
        int g = t + 256 * j;
        ushort4 o;
        o.x = f2bf(rintf(xs[j * 4 + 0] / s));    // RTNE div+round, ints exact in bf16
        o.y = f2bf(rintf(xs[j * 4 + 1] / s));
        o.z = f2bf(rintf(xs[j * 4 + 2] / s));
        o.w = f2bf(rintf(xs[j * 4 + 3] / s));
        ((ushort4*)qr)[g] = o;
    }
}

// ---------------- kernel 2: 256x256 8-phase GEMM (T1+T2+T3+T4+T5 template) ----------
// C[m,n] = scales[m] * sum_k A[m,k]*B[n,k] + bias[n]
// 512 thr = 8 waves (2M x 4N); per-wave output 128x64 split across the two 128-row
// A-halves and two 128-col B-halves -> 2x4x2x2 fragments of 16x16.
// LDS 128 KiB: A[2buf][2half][128x64] @ 0, B same @ 65536. Half-slot = 16 KiB stored
// as 16x32-element subtiles (1024B) with st_16x32 XOR swizzle (k bit4 ^= row bit3),
// applied on BOTH the pre-swizzled global source of global_load_lds (linear dest)
// and the ds_read_b128 lane offsets (rule #21: both-sides-or-neither).
//
// Schedule per K-tile (BK=64): 4 phases = quadrants (ha,hb) = (0,0),(0,1),(1,0),(1,1).
// Each phase: ds_read new frags -> stage ONE half-tile (2x gl16) -> s_barrier ->
// lgkmcnt(0)+sched_barrier(0) -> setprio(1) -> 16 MFMA -> setprio(0) -> s_barrier.
// Staging runs 6 half-tiles ahead; ONE counted s_waitcnt vmcnt(4) per K-tile
// (vmcnt(0) only when draining the last 2 tiles). Hazard ledger:
//   slot A0(buf): read p1 (kept in regs thru p2) ; re-staged at p3 (>=1 barrier later)
//   slot B0(buf): read p1 (kept thru p4)         ; re-staged at p4
//   slot A1(buf): read p3 (kept thru p4)         ; re-staged at next tile's p1
//   slot B1(buf): read p2 (kept thru p4)         ; re-staged at next tile's p2
// vmcnt(4) at each tile boundary leaves exactly the 2 newest half-tiles in flight;
// in-order vmcnt retirement => all 4 half-tiles of the next tile have landed.

#define LREAD(dst, base, imm) \
    asm volatile("ds_read_b128 %0, %1 offset:%2" : "=v"(dst) : "v"(base), "i"(imm))

#define STAGE_A(T, H, BUF) do {                                                  \
    const unsigned short* g_ = pa + (size_t)(H) * 128 * K_DIM + (size_t)(T) * 64;\
    gl16(g_,                      smem3 + ((BUF) * 32768 + (H) * 16384) + tid * 16);          \
    gl16(g_ + (size_t)64 * K_DIM, smem3 + ((BUF) * 32768 + (H) * 16384 + 8192) + tid * 16);   \
} while (0)

#define STAGE_B(T, H, BUF) do {                                                  \
    const unsigned short* g_ = pb + (size_t)(H) * 128 * K_DIM + (size_t)(T) * 64;\
    gl16(g_,                      smem3 + (65536 + (BUF) * 32768 + (H) * 16384) + tid * 16);        \
    gl16(g_ + (size_t)64 * K_DIM, smem3 + (65536 + (BUF) * 32768 + (H) * 16384 + 8192) + tid * 16); \
} while (0)

#define PHASE_TAIL(HA, HB, BFARR) do {                                           \
    __builtin_amdgcn_s_barrier();                                                \
    asm volatile("s_waitcnt lgkmcnt(0)" ::: "memory");                           \
    __builtin_amdgcn_sched_barrier(0);  /* rule #18: pin MFMA after lgkm wait */ \
    __builtin_amdgcn_s_setprio(1);                                               \
    _Pragma("unroll")                                                            \
    for (int s_ = 0; s_ < 2; ++s_)                                               \
      _Pragma("unroll")                                                          \
      for (int i_ = 0; i_ < 4; ++i_)                                             \
        _Pragma("unroll")                                                        \
        for (int j_ = 0; j_ < 2; ++j_)                                           \
          acc[HA][i_][HB][j_] = __builtin_amdgcn_mfma_f32_16x16x32_bf16(         \
              af[i_][s_], BFARR[j_][s_], acc[HA][i_][HB][j_], 0, 0, 0);          \
    __builtin_amdgcn_s_setprio(0);                                               \
} while (0)

#define TILE_STEP(T, BUF, SA1, SB1, SA0, SB0, VMC) do {                          \
    /* phase 1: (ha=0,hb=0); read af(h0)+bf0(h0); stage A1(T+1) -> buf^1 */      \
    _Pragma("unroll")                                                            \
    for (int i_ = 0; i_ < 4; ++i_) {                                             \
        LREAD(af[i_][0], aB, (BUF) * 32768 + (i_ * 2 + 0) * 1024);               \
        LREAD(af[i_][1], aB, (BUF) * 32768 + (i_ * 2 + 1) * 1024);               \
    }                                                                            \
    _Pragma("unroll")                                                            \
    for (int j_ = 0; j_ < 2; ++j_) {                                             \
        LREAD(bf0[j_][0], bB, (BUF) * 32768 + (j_ * 2 + 0) * 1024);              \
        LREAD(bf0[j_][1], bB, (BUF) * 32768 + (j_ * 2 + 1) * 1024);              \
    }                                                                            \
    if (SA1) STAGE_A((T) + 1, 1, (BUF) ^ 1);                                     \
    PHASE_TAIL(0, 0, bf0);                                                       \
    __builtin_amdgcn_s_barrier();                                                \
    /* phase 2: (0,1); read bf1(h1); stage B1(T+1) -> buf^1 */                   \
    _Pragma("unroll")                                                            \
    for (int j_ = 0; j_ < 2; ++j_) {                                             \
        LREAD(bf1[j_][0], bB, (BUF) * 32768 + 16384 + (j_ * 2 + 0) * 1024);      \
        LREAD(bf1[j_][1], bB, (BUF) * 32768 + 16384 + (j_ * 2 + 1) * 1024);      \
    }                                                                            \
    if (SB1) STAGE_B((T) + 1, 1, (BUF) ^ 1);                                     \
    PHASE_TAIL(0, 1, bf1);                                                       \
    __builtin_amdgcn_s_barrier();                                                \
    /* phase 3: (1,0); read af(h1); stage A0(T+2) -> buf */                      \
    _Pragma("unroll")                                                            \
    for (int i_ = 0; i_ < 4; ++i_) {                                             \
        LREAD(af[i_][0], aB, (BUF) * 32768 + 16384 + (i_ * 2 + 0) * 1024);       \
        LREAD(af[i_][1], aB, (BUF) * 32768 + 16384 + (i_ * 2 + 1) * 1024);       \
    }                                                                            \
    if (SA0) STAGE_A((T) + 2, 0, (BUF));                                         \
    PHASE_TAIL(1, 0, bf0);                                                       \
    __builtin_amdgcn_s_barrier();                                                \
    /* phase 4: (1,1); stage B0(T+2) -> buf; counted vmcnt then tile barrier */  \
    if (SB0) STAGE_B((T) + 2, 0, (BUF));                                         \
    PHASE_TAIL(1, 1, bf1);                                                       \
    asm volatile("s_waitcnt vmcnt(%0)" :: "i"(VMC) : "memory");                  \
    __builtin_amdgcn_s_barrier();                                                \
} while (0)

__global__ __launch_bounds__(512, 2) void gemm256_kernel(
        const unsigned short* __restrict__ A,     // [M,K] bf16 (qi)
        const unsigned short* __restrict__ B,     // [N,K] bf16 (Wb)
        const float* __restrict__ scales,         // [M]
        const float* __restrict__ bias,           // [N]
        float* __restrict__ C) {                  // [M,N] f32
    extern __shared__ char smem[];
    ldsptr smem3 = (ldsptr)smem;

    const int tid = threadIdx.x;

    // T1: XCD-bijective swizzle (512 wgs % 8 == 0). tm fastest within an XCD so the
    // 32 CUs of an XCD share one 2MB B-panel per round in their private L2.
    const int wg  = blockIdx.x;
    const int swz = (wg & 7) * 64 + (wg >> 3);
    const int tn  = swz >> 5;                 // 0..15
    const int tm  = swz & 31;                 // 0..31
    const int tmBase = tm * 256, tnBase = tn * 256;

    // staging source decomposition: thread tid's linear 16B LDS slot (call c) holds,
    // under the subtiled+st_16x32 layout, elements (row r0[+64], k = kk0) of the half.
    const int st0  = tid >> 6;                          // subtile id within call 0
    const int r16s = (tid >> 2) & 15;
    const int q4   = tid & 3;
    const int r0   = ((st0 >> 1) << 4) + r16s;          // 0..63 (call1: +64)
    const int kk0  = ((st0 & 1) << 5) + ((q4 * 8) ^ ((r16s >> 3) << 4)); // pre-swizzled k
    const unsigned short* pa = A + (size_t)(tmBase + r0) * K_DIM + kk0;
    const unsigned short* pb = B + (size_t)(tnBase + r0) * K_DIM + kk0;

    // ds_read lane bases (loop-invariant; swizzle XOR folded in once)
    const int lane = tid & 63, wave = tid >> 6;
    const int wr = wave >> 2, wc = wave & 3;            // 2M x 4N waves
    const int laneoff = (lane & 15) * 64 +
        ((((lane >> 4) * 8) ^ (((lane >> 3) & 1) << 4)) << 1);
    ldsptr aB = smem3 + wr * 8192 + laneoff;            // + imm: buf*32768+h*16384+(i*2+s)*1024
    ldsptr bB = smem3 + 65536 + wc * 4096 + laneoff;    // + imm: buf*32768+h*16384+(j*2+s)*1024

    bf16x8 af[4][2], bf0[2][2], bf1[2][2];
    f32x4 acc[2][4][2][2];
    const f32x4 z = { 0.f, 0.f, 0.f, 0.f };
#pragma unroll
    for (int a0 = 0; a0 < 2; ++a0)
#pragma unroll
      for (int a1 = 0; a1 < 4; ++a1)
#pragma unroll
        for (int a2 = 0; a2 < 2; ++a2)
#pragma unroll
          for (int a3 = 0; a3 < 2; ++a3) acc[a0][a1][a2][a3] = z;

    // prologue: tile0 (A0,B0,A1,B1) -> buf0, tile1 (A0,B0) -> buf1.
    // vmcnt(4) => tile0's 8 loads landed, 2 half-tiles (4 loads) in flight.
    STAGE_A(0, 0, 0); STAGE_B(0, 0, 0); STAGE_A(0, 1, 0); STAGE_B(0, 1, 0);
    STAGE_A(1, 0, 1); STAGE_B(1, 0, 1);
    asm volatile("s_waitcnt vmcnt(4)" ::: "memory");
    __builtin_amdgcn_s_barrier();

    // main loop: tiles 0..61 fully staged; tiles 62,63 drain (vmcnt 4 -> 0).
    for (int t = 0; t < NT - 2; t += 2) {
        TILE_STEP(t,     0, 1, 1, 1, 1, 4);
        TILE_STEP(t + 1, 1, 1, 1, 1, 1, 4);
    }
    TILE_STEP(NT - 2, 0, 1, 1, 0, 0, 0);
    TILE_STEP(NT - 1, 1, 0, 0, 0, 0, 0);

    // epilogue: D row = (lane>>4)*4+reg (A side), col = lane&15 (B side) — m89 layout
#pragma unroll
    for (int ha = 0; ha < 2; ++ha)
#pragma unroll
      for (int i = 0; i < 4; ++i) {
        const int rbase = tmBase + ha * 128 + wr * 64 + i * 16 + (lane >> 4) * 4;
        float sc[4];
#pragma unroll
        for (int r = 0; r < 4; ++r) sc[r] = scales[rbase + r];
#pragma unroll
        for (int hb = 0; hb < 2; ++hb)
#pragma unroll
          for (int j = 0; j < 2; ++j) {
            const int col = tnBase + hb * 128 + wc * 32 + j * 16 + (lane & 15);
            const float bb = bias[col];
#pragma unroll
            for (int r = 0; r < 4; ++r)
                C[(size_t)(rbase + r) * N_DIM + col] = sc[r] * acc[ha][i][hb][j][r] + bb;
          }
      }
}

extern "C" void kernel_launch(void* const* d_in, const int* in_sizes, int n_in,
                              void* d_out, int out_size, void* d_ws, size_t ws_size,
                              hipStream_t stream) {
    const float* x    = (const float*)d_in[0];   // (4,2048,4096)
    const float* w    = (const float*)d_in[1];   // (4096,4096)
    const float* bias = (const float*)d_in[2];   // (1,4096)
    const float* ss   = (const float*)d_in[3];   // (1,4096)
    float* out = (float*)d_out;

    // workspace layout: qi bf16 [8192*4096] | scales f32 [8192] | Wb bf16 [4096*4096]
    unsigned short* qi = (unsigned short*)d_ws;
    float* scales = (float*)((char*)d_ws + (size_t)T_TOK * K_DIM * 2);
    unsigned short* wb = (unsigned short*)((char*)d_ws + (size_t)T_TOK * K_DIM * 2 + T_TOK * 4);

    wconv_kernel<<<(N_DIM * K_DIM) / (256 * 4), 256, 0, stream>>>(w, wb);
    sparsequant_kernel<<<T_TOK, 256, 0, stream>>>(x, ss, qi, scales);

    // 128 KiB dynamic LDS (> 64 KiB default): raise the cap; harmless if redundant.
    (void)hipFuncSetAttribute(reinterpret_cast<const void*>(gemm256_kernel),
                              hipFuncAttributeMaxDynamicSharedMemorySize, 131072);
    gemm256_kernel<<<dim3(512), dim3(512), 131072, stream>>>(qi, wb, scales, bias, out);
}

// Round 2
// 516.709 us; speedup vs baseline: 1.1776x; 1.0015x over previous
//
#include <hip/hip_runtime.h>
#include <hip/hip_bf16.h>
#include <stdint.h>

// Problem dims (fixed by reference): x (4,2048,4096) f32, W (4096,4096) f32,
// bias (4096) f32, sparsity_scale (4096) f32. Tokens T = 8192.
#define T_TOK 8192
#define K_DIM 4096
#define N_DIM 4096
#define NT 64            // K_DIM / 64  (K-tiles of BK=64)

typedef short bf16x8 __attribute__((ext_vector_type(8)));
typedef float f32x4  __attribute__((ext_vector_type(4)));
typedef __attribute__((address_space(3))) char* ldsptr;

// RTNE f32 -> bf16 (bit manipulation; matches numpy/jax casts for finite vals)
__device__ __forceinline__ unsigned short f2bf(float f) {
    uint32_t u = __float_as_uint(f);
    u += 0x7FFFu + ((u >> 16) & 1u);
    return (unsigned short)(u >> 16);
}

// async global->LDS, 16B per lane. LDS dest must be wave-uniform base + lane*16.
__device__ __forceinline__ void gl16(const unsigned short* g, ldsptr l) {
    __builtin_amdgcn_global_load_lds(
        (const __attribute__((address_space(1))) void*)g,
        (__attribute__((address_space(3))) void*)l, 16, 0, 0);
}

// ---------------- kernel 0: W f32 -> bf16 ----------------
__global__ __launch_bounds__(256) void wconv_kernel(const float* __restrict__ w,
                                                    unsigned short* __restrict__ wb) {
    int i = (blockIdx.x * 256 + threadIdx.x) * 4;   // 4 floats per thread
    float4 v = *(const float4*)(w + i);
    ushort4 o;
    o.x = f2bf(v.x); o.y = f2bf(v.y); o.z = f2bf(v.z); o.w = f2bf(v.w);
    *(ushort4*)(wb + i) = o;
}

// ------- kernel 1: 2:4 sparsify + per-token absmax quant -> qi (bf16 ints), s -------
__global__ __launch_bounds__(256) void sparsequant_kernel(
        const float* __restrict__ x, const float* __restrict__ ss,
        unsigned short* __restrict__ qi, float* __restrict__ scales) {
    const int row = blockIdx.x;
    const int t = threadIdx.x;
    const float* xr = x + (size_t)row * K_DIM;

    float xs[16];
    float amax = 0.f;
#pragma unroll
    for (int j = 0; j < 4; ++j) {
        int g = t + 256 * j;                     // group index 0..1023
        float4 v  = ((const float4*)xr)[g];
        float4 sv = ((const float4*)ss)[g];
        float e[4] = { v.x, v.y, v.z, v.w };
        float m[4] = { fabsf(v.x) * sv.x, fabsf(v.y) * sv.y,
                       fabsf(v.z) * sv.z, fabsf(v.w) * sv.w };
#pragma unroll
        for (int a = 0; a < 4; ++a) {
            int cnt = 0;
#pragma unroll
            for (int b = 0; b < 4; ++b) {
                if (b == a) continue;
                bool less = (m[b] < m[a]) || (m[b] == m[a] && b < a);
                cnt += less ? 1 : 0;
            }
            float kept = (cnt >= 2) ? e[a] : 0.f;   // zero the 2 smallest
            xs[j * 4 + a] = kept;
            amax = fmaxf(amax, fabsf(kept));
        }
    }
#pragma unroll
    for (int off = 32; off >= 1; off >>= 1)
        amax = fmaxf(amax, __shfl_xor(amax, off, 64));
    __shared__ float wm[4];
    int wave = t >> 6, lane = t & 63;
    if (lane == 0) wm[wave] = amax;
    __syncthreads();
    amax = fmaxf(fmaxf(wm[0], wm[1]), fmaxf(wm[2], wm[3]));

    float s = fmaxf(amax, 1e-5f) / 127.0f;   // same f32 ops as reference
    if (t == 0) scales[row] = s;

    unsigned short* qr = qi + (size_t)row * K_DIM;
#pragma unroll
    for (int j = 0; j < 4; ++j) {
        int g = t + 256 * j;
        ushort4 o;
        o.x = f2bf(rintf(xs[j * 4 + 0] / s));
        o.y = f2bf(rintf(xs[j * 4 + 1] / s));
        o.z = f2bf(rintf(xs[j * 4 + 2] / s));
        o.w = f2bf(rintf(xs[j * 4 + 3] / s));
        ((ushort4*)qr)[g] = o;
    }
}

// ---------------- kernel 2: 256x256 pipelined-lgkm GEMM ----------------
// C[m,n] = scales[m] * sum_k A[m,k]*B[n,k] + bias[n]
// Same geometry/LDS/swizzle as r1 (8 waves 2Mx4N, 128 KiB, st_16x32 both-sides).
// NEW schedule: quadrant order (0,0),(0,1),(1,1),(1,0); register reads pipelined
// one phase ahead with COUNTED lgkm waits; ONE barrier per phase (4/tile).
// Per tile T (buf b), steady state:
//  p1: read bf1(T)[4]; stage A1(T+1)->b^1; lgkmcnt(4) [af,bf0 done, bf1 fly];
//      MFMA(0,0); BAR
//  p2: stage B1(T+1)->b^1; lgkmcnt(0) [=bf1 done]; MFMA(0,1); read af1(T)[8]; BAR
//  p3: stage A0(T+2)->b;   lgkmcnt(0) [=af1 done]; MFMA(1,1); vmcnt(6); BAR
//  p4: stage B0(T+2)->b;   (no wait needed) MFMA(1,0);
//      read af0(T+1)+bf0(T+1)[12] from b^1; vmcnt(4); BAR
// vmcnt ledger (stages/tile: A1'@p1,B1'@p2,A0''@p3,B0''@p4; 2 loads each):
//  - vmcnt(6)@p3-end retires A0(T+1),B0(T+1) -> p4's 12 reads (after p3 barrier) safe
//  - vmcnt(4)@p4-end retires A1(T+1),B1(T+1) -> T+1's p1/p2 reads safe
// lgkm queues hold ONLY our ds_reads (kernarg s_loads drained pre-loop; gl16=vmcnt),
// DS ops retire in-order => counted waits exact.
// Slot overwrite ledger (>=1 barrier between readers' wait and re-stage): A1(b^1)
// readers waited T-1 p3, staged T p1 (2 bars); B1: waited T-1 p2, staged T p2 (3);
// A0(b): waited T p1, staged T p3 (2); B0(b): waited T p1, staged T p4 (3). All ok
// incl. max 1-phase wave drift (barrier every phase end).

#define LREAD(dst, base, imm) \
    asm volatile("ds_read_b128 %0, %1 offset:%2" : "=v"(dst) : "v"(base), "i"(imm))

#define WAIT_LGKM(N) do {                                           \
    asm volatile("s_waitcnt lgkmcnt(%0)" :: "i"(N) : "memory");     \
    __builtin_amdgcn_sched_barrier(0);  /* rule #18 */              \
} while (0)

#define WAIT_VM(N) asm volatile("s_waitcnt vmcnt(%0)" :: "i"(N) : "memory")
#define BAR() __builtin_amdgcn_s_barrier()
#define NOP do {} while (0)

#define STAGE_A(T, H, BUF) do {                                                  \
    const unsigned short* g_ = pa + (size_t)(H) * 128 * K_DIM + (size_t)(T) * 64;\
    gl16(g_,                      smem3 + ((BUF) * 32768 + (H) * 16384) + tid * 16);          \
    gl16(g_ + (size_t)64 * K_DIM, smem3 + ((BUF) * 32768 + (H) * 16384 + 8192) + tid * 16);   \
} while (0)

#define STAGE_B(T, H, BUF) do {                                                  \
    const unsigned short* g_ = pb + (size_t)(H) * 128 * K_DIM + (size_t)(T) * 64;\
    gl16(g_,                      smem3 + (65536 + (BUF) * 32768 + (H) * 16384) + tid * 16);        \
    gl16(g_ + (size_t)64 * K_DIM, smem3 + (65536 + (BUF) * 32768 + (H) * 16384 + 8192) + tid * 16); \
} while (0)

#define READ_AF(BUF, H) do {                                                     \
    _Pragma("unroll")                                                            \
    for (int i_ = 0; i_ < 4; ++i_) {                                             \
        LREAD(af[i_][0], aB, (BUF) * 32768 + (H) * 16384 + (i_ * 2 + 0) * 1024); \
        LREAD(af[i_][1], aB, (BUF) * 32768 + (H) * 16384 + (i_ * 2 + 1) * 1024); \
    }                                                                            \
} while (0)

#define READ_BF(ARR, BUF, H) do {                                                \
    _Pragma("unroll")                                                            \
    for (int j_ = 0; j_ < 2; ++j_) {                                             \
        LREAD(ARR[j_][0], bB, (BUF) * 32768 + (H) * 16384 + (j_ * 2 + 0) * 1024);\
        LREAD(ARR[j_][1], bB, (BUF) * 32768 + (H) * 16384 + (j_ * 2 + 1) * 1024);\
    }                                                                            \
} while (0)

#define MFMA_C(HA, HB, BF) do {                                                  \
    __builtin_amdgcn_s_setprio(1);                                               \
    _Pragma("unroll")                                                            \
    for (int s_ = 0; s_ < 2; ++s_)                                               \
      _Pragma("unroll")                                                          \
      for (int i_ = 0; i_ < 4; ++i_)                                             \
        _Pragma("unroll")                                                        \
        for (int j_ = 0; j_ < 2; ++j_)                                           \
          acc[HA][i_][HB][j_] = __builtin_amdgcn_mfma_f32_16x16x32_bf16(         \
              af[i_][s_], BF[j_][s_], acc[HA][i_][HB][j_], 0, 0, 0);             \
    __builtin_amdgcn_s_setprio(0);                                               \
} while (0)

// PF: prefetch next tile's (0,0) frags from buf NBUF (af + bf0, 12 reads)
#define PF_NEXT(NBUF) do { READ_AF(NBUF, 0); READ_BF(bf0, NBUF, 0); } while (0)

#define TILE(BUF, S1, S2, S3, S4, PF, W3, W4) do {                               \
    /* p1: (0,0) */                                                              \
    READ_BF(bf1, BUF, 1);                                                        \
    S1;                                                                          \
    WAIT_LGKM(4);                                                                \
    MFMA_C(0, 0, bf0);                                                           \
    BAR();                                                                       \
    /* p2: (0,1) */                                                              \
    S2;                                                                          \
    WAIT_LGKM(0);                                                                \
    MFMA_C(0, 1, bf1);                                                           \
    READ_AF(BUF, 1);                                                             \
    BAR();                                                                       \
    /* p3: (1,1) */                                                              \
    S3;                                                                          \
    WAIT_LGKM(0);                                                                \
    MFMA_C(1, 1, bf1);                                                           \
    W3;                                                                          \
    BAR();                                                                       \
    /* p4: (1,0) */                                                              \
    S4;                                                                          \
    MFMA_C(1, 0, bf0);                                                           \
    PF;                                                                          \
    W4;                                                                          \
    BAR();                                                                       \
} while (0)

__global__ __launch_bounds__(512, 2) void gemm256_kernel(
        const unsigned short* __restrict__ A,     // [M,K] bf16 (qi)
        const unsigned short* __restrict__ B,     // [N,K] bf16 (Wb)
        const float* __restrict__ scales,         // [M]
        const float* __restrict__ bias,           // [N]
        float* __restrict__ C) {                  // [M,N] f32
    extern __shared__ char smem[];
    ldsptr smem3 = (ldsptr)smem;

    const int tid = threadIdx.x;

    // T1: XCD-bijective swizzle (512 wgs % 8 == 0), tm fastest within an XCD.
    const int wg  = blockIdx.x;
    const int swz = (wg & 7) * 64 + (wg >> 3);
    const int tn  = swz >> 5;                 // 0..15
    const int tm  = swz & 31;                 // 0..31
    const int tmBase = tm * 256, tnBase = tn * 256;

    // staging source decomposition (pre-swizzled global source, linear LDS dest)
    const int st0  = tid >> 6;                          // subtile id within call 0
    const int r16s = (tid >> 2) & 15;
    const int q4   = tid & 3;
    const int r0   = ((st0 >> 1) << 4) + r16s;          // 0..63 (call1: +64)
    const int kk0  = ((st0 & 1) << 5) + ((q4 * 8) ^ ((r16s >> 3) << 4));
    const unsigned short* pa = A + (size_t)(tmBase + r0) * K_DIM + kk0;
    const unsigned short* pb = B + (size_t)(tnBase + r0) * K_DIM + kk0;

    // ds_read lane bases (loop-invariant; swizzle XOR folded in once)
    const int lane = tid & 63, wave = tid >> 6;
    const int wr = wave >> 2, wc = wave & 3;            // 2M x 4N waves
    const int laneoff = (lane & 15) * 64 +
        ((((lane >> 4) * 8) ^ (((lane >> 3) & 1) << 4)) << 1);
    ldsptr aB = smem3 + wr * 8192 + laneoff;
    ldsptr bB = smem3 + 65536 + wc * 4096 + laneoff;

    bf16x8 af[4][2], bf0[2][2], bf1[2][2];
    f32x4 acc[2][4][2][2];
    const f32x4 z = { 0.f, 0.f, 0.f, 0.f };
#pragma unroll
    for (int a0 = 0; a0 < 2; ++a0)
#pragma unroll
      for (int a1 = 0; a1 < 4; ++a1)
#pragma unroll
        for (int a2 = 0; a2 < 2; ++a2)
#pragma unroll
          for (int a3 = 0; a3 < 2; ++a3) acc[a0][a1][a2][a3] = z;

    // prologue: stage tile0 (A0,B0,A1,B1)->buf0, tile1 (A0,B0)->buf1.
    // vmcnt(4): first 4 half-tiles landed, A0(1)/B0(1) in flight.
    STAGE_A(0, 0, 0); STAGE_B(0, 0, 0); STAGE_A(0, 1, 0); STAGE_B(0, 1, 0);
    STAGE_A(1, 0, 1); STAGE_B(1, 0, 1);
    WAIT_VM(4);
    BAR();
    READ_AF(0, 0);          // af0(0)
    READ_BF(bf0, 0, 0);     // bf0(0)

    // steady tiles 0..61 (pairs: buf 0 then buf 1)
    for (int t = 0; t < NT - 2; t += 2) {
        TILE(0, STAGE_A(t + 1, 1, 1), STAGE_B(t + 1, 1, 1),
                STAGE_A(t + 2, 0, 0), STAGE_B(t + 2, 0, 0),
                PF_NEXT(1), WAIT_VM(6), WAIT_VM(4));
        TILE(1, STAGE_A(t + 2, 1, 0), STAGE_B(t + 2, 1, 0),
                STAGE_A(t + 3, 0, 1), STAGE_B(t + 3, 0, 1),
                PF_NEXT(0), WAIT_VM(6), WAIT_VM(4));
    }
    // tile 62 (buf 0): only A1/B1(63) remain to stage; drain vmcnt by the end.
    TILE(0, STAGE_A(63, 1, 1), STAGE_B(63, 1, 1), NOP, NOP,
            PF_NEXT(1), WAIT_VM(4), WAIT_VM(0));
    // tile 63 (buf 1): nothing to stage or prefetch beyond.
    TILE(1, NOP, NOP, NOP, NOP, NOP, NOP, NOP);

    // epilogue: D row = (lane>>4)*4+reg (A side), col = lane&15 (B side)
#pragma unroll
    for (int ha = 0; ha < 2; ++ha)
#pragma unroll
      for (int i = 0; i < 4; ++i) {
        const int rbase = tmBase + ha * 128 + wr * 64 + i * 16 + (lane >> 4) * 4;
        float sc[4];
#pragma unroll
        for (int r = 0; r < 4; ++r) sc[r] = scales[rbase + r];
#pragma unroll
        for (int hb = 0; hb < 2; ++hb)
#pragma unroll
          for (int j = 0; j < 2; ++j) {
            const int col = tnBase + hb * 128 + wc * 32 + j * 16 + (lane & 15);
            const float bb = bias[col];
#pragma unroll
            for (int r = 0; r < 4; ++r)
                C[(size_t)(rbase + r) * N_DIM + col] = sc[r] * acc[ha][i][hb][j][r] + bb;
          }
      }
}

extern "C" void kernel_launch(void* const* d_in, const int* in_sizes, int n_in,
                              void* d_out, int out_size, void* d_ws, size_t ws_size,
                              hipStream_t stream) {
    const float* x    = (const float*)d_in[0];   // (4,2048,4096)
    const float* w    = (const float*)d_in[1];   // (4096,4096)
    const float* bias = (const float*)d_in[2];   // (1,4096)
    const float* ss   = (const float*)d_in[3];   // (1,4096)
    float* out = (float*)d_out;

    // workspace layout: qi bf16 [8192*4096] | scales f32 [8192] | Wb bf16 [4096*4096]
    unsigned short* qi = (unsigned short*)d_ws;
    float* scales = (float*)((char*)d_ws + (size_t)T_TOK * K_DIM * 2);
    unsigned short* wb = (unsigned short*)((char*)d_ws + (size_t)T_TOK * K_DIM * 2 + T_TOK * 4);

    wconv_kernel<<<(N_DIM * K_DIM) / (256 * 4), 256, 0, stream>>>(w, wb);
    sparsequant_kernel<<<T_TOK, 256, 0, stream>>>(x, ss, qi, scales);

    (void)hipFuncSetAttribute(reinterpret_cast<const void*>(gemm256_kernel),
                              hipFuncAttributeMaxDynamicSharedMemorySize, 131072);
    gemm256_kernel<<<dim3(512), dim3(512), 131072, stream>>>(qi, wb, scales, bias, out);
}

// Round 4
// 462.841 us; speedup vs baseline: 1.3147x; 1.1164x over previous
//
#include <hip/hip_runtime.h>
#include <hip/hip_bf16.h>
#include <stdint.h>

// Problem dims (fixed by reference): x (4,2048,4096) f32, W (4096,4096) f32,
// bias (4096) f32, sparsity_scale (4096) f32. Tokens T = 8192.
#define T_TOK 8192
#define K_DIM 4096
#define N_DIM 4096
#define NT 64            // K_DIM / 64  (K-tiles of BK=64)
#define WCONV_BLOCKS 16384   // (4096*4096)/(256*4)

typedef short bf16x8 __attribute__((ext_vector_type(8)));
typedef float f32x4  __attribute__((ext_vector_type(4)));
typedef __attribute__((address_space(3))) char* ldsptr;

// RTNE f32 -> bf16 (bit manipulation; matches numpy/jax casts for finite vals)
__device__ __forceinline__ unsigned short f2bf(float f) {
    uint32_t u = __float_as_uint(f);
    u += 0x7FFFu + ((u >> 16) & 1u);
    return (unsigned short)(u >> 16);
}

// async global->LDS, 16B per lane. LDS dest must be wave-uniform base + lane*16.
__device__ __forceinline__ void gl16(const unsigned short* g, ldsptr l) {
    __builtin_amdgcn_global_load_lds(
        (const __attribute__((address_space(1))) void*)g,
        (__attribute__((address_space(3))) void*)l, 16, 0, 0);
}

// ---------------- kernel 0+1 fused: W f32->bf16  ||  2:4 sparsify + quant ----------
// blocks [0, WCONV_BLOCKS): weight convert; blocks [WCONV_BLOCKS, +T_TOK): sparsequant.
// One launch -> one device drain instead of two, and the two memory-bound phases
// overlap at the boundary. Branch is block-uniform (no divergence).
__global__ __launch_bounds__(256) void prep_kernel(
        const float* __restrict__ w, unsigned short* __restrict__ wb,
        const float* __restrict__ x, const float* __restrict__ ss,
        unsigned short* __restrict__ qi, float* __restrict__ scales) {
    const int t = threadIdx.x;
    if (blockIdx.x < WCONV_BLOCKS) {
        int i = (blockIdx.x * 256 + t) * 4;   // 4 floats per thread
        float4 v = *(const float4*)(w + i);
        ushort4 o;
        o.x = f2bf(v.x); o.y = f2bf(v.y); o.z = f2bf(v.z); o.w = f2bf(v.w);
        *(ushort4*)(wb + i) = o;
        return;
    }
    const int row = blockIdx.x - WCONV_BLOCKS;
    const float* xr = x + (size_t)row * K_DIM;

    float xs[16];
    float amax = 0.f;
#pragma unroll
    for (int j = 0; j < 4; ++j) {
        int g = t + 256 * j;                     // group index 0..1023
        float4 v  = ((const float4*)xr)[g];
        float4 sv = ((const float4*)ss)[g];
        float e[4] = { v.x, v.y, v.z, v.w };
        float m[4] = { fabsf(v.x) * sv.x, fabsf(v.y) * sv.y,
                       fabsf(v.z) * sv.z, fabsf(v.w) * sv.w };
#pragma unroll
        for (int a = 0; a < 4; ++a) {
            int cnt = 0;
#pragma unroll
            for (int b = 0; b < 4; ++b) {
                if (b == a) continue;
                // strict-order key (metric, index): matches stable top_k of smallest
                bool less = (m[b] < m[a]) || (m[b] == m[a] && b < a);
                cnt += less ? 1 : 0;
            }
            float kept = (cnt >= 2) ? e[a] : 0.f;   // zero the 2 smallest
            xs[j * 4 + a] = kept;
            amax = fmaxf(amax, fabsf(kept));
        }
    }
#pragma unroll
    for (int off = 32; off >= 1; off >>= 1)
        amax = fmaxf(amax, __shfl_xor(amax, off, 64));
    __shared__ float wm[4];
    int wave = t >> 6, lane = t & 63;
    if (lane == 0) wm[wave] = amax;
    __syncthreads();
    amax = fmaxf(fmaxf(wm[0], wm[1]), fmaxf(wm[2], wm[3]));

    float s = fmaxf(amax, 1e-5f) / 127.0f;   // same f32 ops as reference
    if (t == 0) scales[row] = s;

    unsigned short* qr = qi + (size_t)row * K_DIM;
#pragma unroll
    for (int j = 0; j < 4; ++j) {
        int g = t + 256 * j;
        ushort4 o;
        o.x = f2bf(rintf(xs[j * 4 + 0] / s));    // RTNE div+round, ints exact in bf16
        o.y = f2bf(rintf(xs[j * 4 + 1] / s));
        o.z = f2bf(rintf(xs[j * 4 + 2] / s));
        o.w = f2bf(rintf(xs[j * 4 + 3] / s));
        ((ushort4*)qr)[g] = o;
    }
}

// ---------------- kernel 2: 256x256 pipelined-lgkm GEMM ----------------
// C[m,n] = scales[m] * sum_k A[m,k]*B[n,k] + bias[n]
// Geometry/LDS/swizzle as r1 (8 waves 2Mx4N, 128 KiB, st_16x32 both-sides).
// Schedule: quadrant order (0,0),(0,1),(1,1),(1,0); register reads pipelined
// one phase ahead with COUNTED lgkm waits; ONE barrier per phase (4/tile).
// Hazard ledger verified in r2 (passed); unchanged this round.
// NEW (r3 resubmit): 2D-chunked XCD swizzle — 8 chunks of 8tm x 8tn so each
// XCD's L2 sees 16MB A + 16MB B instead of 64MB A + 4MB B. FETCH 541->~260MB.

#define LREAD(dst, base, imm) \
    asm volatile("ds_read_b128 %0, %1 offset:%2" : "=v"(dst) : "v"(base), "i"(imm))

#define WAIT_LGKM(N) do {                                           \
    asm volatile("s_waitcnt lgkmcnt(%0)" :: "i"(N) : "memory");     \
    __builtin_amdgcn_sched_barrier(0);  /* rule #18 */              \
} while (0)

#define WAIT_VM(N) asm volatile("s_waitcnt vmcnt(%0)" :: "i"(N) : "memory")
#define BAR() __builtin_amdgcn_s_barrier()
#define NOP do {} while (0)

#define STAGE_A(T, H, BUF) do {                                                  \
    const unsigned short* g_ = pa + (size_t)(H) * 128 * K_DIM + (size_t)(T) * 64;\
    gl16(g_,                      smem3 + ((BUF) * 32768 + (H) * 16384) + tid * 16);          \
    gl16(g_ + (size_t)64 * K_DIM, smem3 + ((BUF) * 32768 + (H) * 16384 + 8192) + tid * 16);   \
} while (0)

#define STAGE_B(T, H, BUF) do {                                                  \
    const unsigned short* g_ = pb + (size_t)(H) * 128 * K_DIM + (size_t)(T) * 64;\
    gl16(g_,                      smem3 + (65536 + (BUF) * 32768 + (H) * 16384) + tid * 16);        \
    gl16(g_ + (size_t)64 * K_DIM, smem3 + (65536 + (BUF) * 32768 + (H) * 16384 + 8192) + tid * 16); \
} while (0)

#define READ_AF(BUF, H) do {                                                     \
    _Pragma("unroll")                                                            \
    for (int i_ = 0; i_ < 4; ++i_) {                                             \
        LREAD(af[i_][0], aB, (BUF) * 32768 + (H) * 16384 + (i_ * 2 + 0) * 1024); \
        LREAD(af[i_][1], aB, (BUF) * 32768 + (H) * 16384 + (i_ * 2 + 1) * 1024); \
    }                                                                            \
} while (0)

#define READ_BF(ARR, BUF, H) do {                                                \
    _Pragma("unroll")                                                            \
    for (int j_ = 0; j_ < 2; ++j_) {                                             \
        LREAD(ARR[j_][0], bB, (BUF) * 32768 + (H) * 16384 + (j_ * 2 + 0) * 1024);\
        LREAD(ARR[j_][1], bB, (BUF) * 32768 + (H) * 16384 + (j_ * 2 + 1) * 1024);\
    }                                                                            \
} while (0)

#define MFMA_C(HA, HB, BF) do {                                                  \
    __builtin_amdgcn_s_setprio(1);                                               \
    _Pragma("unroll")                                                            \
    for (int s_ = 0; s_ < 2; ++s_)                                               \
      _Pragma("unroll")                                                          \
      for (int i_ = 0; i_ < 4; ++i_)                                             \
        _Pragma("unroll")                                                        \
        for (int j_ = 0; j_ < 2; ++j_)                                           \
          acc[HA][i_][HB][j_] = __builtin_amdgcn_mfma_f32_16x16x32_bf16(         \
              af[i_][s_], BF[j_][s_], acc[HA][i_][HB][j_], 0, 0, 0);             \
    __builtin_amdgcn_s_setprio(0);                                               \
} while (0)

// PF: prefetch next tile's (0,0) frags from buf NBUF (af + bf0, 12 reads)
#define PF_NEXT(NBUF) do { READ_AF(NBUF, 0); READ_BF(bf0, NBUF, 0); } while (0)

#define TILE(BUF, S1, S2, S3, S4, PF, W3, W4) do {                               \
    /* p1: (0,0) */                                                              \
    READ_BF(bf1, BUF, 1);                                                        \
    S1;                                                                          \
    WAIT_LGKM(4);                                                                \
    MFMA_C(0, 0, bf0);                                                           \
    BAR();                                                                       \
    /* p2: (0,1) */                                                              \
    S2;                                                                          \
    WAIT_LGKM(0);                                                                \
    MFMA_C(0, 1, bf1);                                                           \
    READ_AF(BUF, 1);                                                             \
    BAR();                                                                       \
    /* p3: (1,1) */                                                              \
    S3;                                                                          \
    WAIT_LGKM(0);                                                                \
    MFMA_C(1, 1, bf1);                                                           \
    W3;                                                                          \
    BAR();                                                                       \
    /* p4: (1,0) */                                                              \
    S4;                                                                          \
    MFMA_C(1, 0, bf0);                                                           \
    PF;                                                                          \
    W4;                                                                          \
    BAR();                                                                       \
} while (0)

__global__ __launch_bounds__(512, 2) void gemm256_kernel(
        const unsigned short* __restrict__ A,     // [M,K] bf16 (qi)
        const unsigned short* __restrict__ B,     // [N,K] bf16 (Wb)
        const float* __restrict__ scales,         // [M]
        const float* __restrict__ bias,           // [N]
        float* __restrict__ C) {                  // [M,N] f32
    extern __shared__ char smem[];
    ldsptr smem3 = (ldsptr)smem;

    const int tid = threadIdx.x;

    // T1 (r3): 2D-chunked bijective XCD swizzle. Grid = 32(tm) x 16(tn) = 512 wgs;
    // 8 XCDs -> 4x2 chunks of 8x8 tiles. Per XCD: 8 A-panels (16MB) + 8 B-panels
    // (16MB) instead of all-A (64MB) + 2 B-panels. Bijective: (xcd, idx) <-> (tm, tn).
    const int wg   = blockIdx.x;
    const int xcd  = wg & 7;
    const int idx  = wg >> 3;                 // 0..63 within chunk
    const int tm   = (xcd >> 1) * 8 + (idx & 7);    // 0..31
    const int tn   = (xcd & 1) * 8 + (idx >> 3);    // 0..15
    const int tmBase = tm * 256, tnBase = tn * 256;

    // staging source decomposition (pre-swizzled global source, linear LDS dest)
    const int st0  = tid >> 6;                          // subtile id within call 0
    const int r16s = (tid >> 2) & 15;
    const int q4   = tid & 3;
    const int r0   = ((st0 >> 1) << 4) + r16s;          // 0..63 (call1: +64)
    const int kk0  = ((st0 & 1) << 5) + ((q4 * 8) ^ ((r16s >> 3) << 4));
    const unsigned short* pa = A + (size_t)(tmBase + r0) * K_DIM + kk0;
    const unsigned short* pb = B + (size_t)(tnBase + r0) * K_DIM + kk0;

    // ds_read lane bases (loop-invariant; swizzle XOR folded in once)
    const int lane = tid & 63, wave = tid >> 6;
    const int wr = wave >> 2, wc = wave & 3;            // 2M x 4N waves
    const int laneoff = (lane & 15) * 64 +
        ((((lane >> 4) * 8) ^ (((lane >> 3) & 1) << 4)) << 1);
    ldsptr aB = smem3 + wr * 8192 + laneoff;
    ldsptr bB = smem3 + 65536 + wc * 4096 + laneoff;

    bf16x8 af[4][2], bf0[2][2], bf1[2][2];
    f32x4 acc[2][4][2][2];
    const f32x4 z = { 0.f, 0.f, 0.f, 0.f };
#pragma unroll
    for (int a0 = 0; a0 < 2; ++a0)
#pragma unroll
      for (int a1 = 0; a1 < 4; ++a1)
#pragma unroll
        for (int a2 = 0; a2 < 2; ++a2)
#pragma unroll
          for (int a3 = 0; a3 < 2; ++a3) acc[a0][a1][a2][a3] = z;

    // prologue: stage tile0 (A0,B0,A1,B1)->buf0, tile1 (A0,B0)->buf1.
    // vmcnt(4): first 4 half-tiles landed, A0(1)/B0(1) in flight.
    STAGE_A(0, 0, 0); STAGE_B(0, 0, 0); STAGE_A(0, 1, 0); STAGE_B(0, 1, 0);
    STAGE_A(1, 0, 1); STAGE_B(1, 0, 1);
    WAIT_VM(4);
    BAR();
    READ_AF(0, 0);          // af0(0)
    READ_BF(bf0, 0, 0);     // bf0(0)

    // steady tiles 0..61 (pairs: buf 0 then buf 1)
    for (int t = 0; t < NT - 2; t += 2) {
        TILE(0, STAGE_A(t + 1, 1, 1), STAGE_B(t + 1, 1, 1),
                STAGE_A(t + 2, 0, 0), STAGE_B(t + 2, 0, 0),
                PF_NEXT(1), WAIT_VM(6), WAIT_VM(4));
        TILE(1, STAGE_A(t + 2, 1, 0), STAGE_B(t + 2, 1, 0),
                STAGE_A(t + 3, 0, 1), STAGE_B(t + 3, 0, 1),
                PF_NEXT(0), WAIT_VM(6), WAIT_VM(4));
    }
    // tile 62 (buf 0): only A1/B1(63) remain to stage; drain vmcnt by the end.
    TILE(0, STAGE_A(63, 1, 1), STAGE_B(63, 1, 1), NOP, NOP,
            PF_NEXT(1), WAIT_VM(4), WAIT_VM(0));
    // tile 63 (buf 1): nothing to stage or prefetch beyond.
    TILE(1, NOP, NOP, NOP, NOP, NOP, NOP, NOP);

    // epilogue: D row = (lane>>4)*4+reg (A side), col = lane&15 (B side)
#pragma unroll
    for (int ha = 0; ha < 2; ++ha)
#pragma unroll
      for (int i = 0; i < 4; ++i) {
        const int rbase = tmBase + ha * 128 + wr * 64 + i * 16 + (lane >> 4) * 4;
        float sc[4];
#pragma unroll
        for (int r = 0; r < 4; ++r) sc[r] = scales[rbase + r];
#pragma unroll
        for (int hb = 0; hb < 2; ++hb)
#pragma unroll
          for (int j = 0; j < 2; ++j) {
            const int col = tnBase + hb * 128 + wc * 32 + j * 16 + (lane & 15);
            const float bb = bias[col];
#pragma unroll
            for (int r = 0; r < 4; ++r)
                C[(size_t)(rbase + r) * N_DIM + col] = sc[r] * acc[ha][i][hb][j][r] + bb;
          }
      }
}

extern "C" void kernel_launch(void* const* d_in, const int* in_sizes, int n_in,
                              void* d_out, int out_size, void* d_ws, size_t ws_size,
                              hipStream_t stream) {
    const float* x    = (const float*)d_in[0];   // (4,2048,4096)
    const float* w    = (const float*)d_in[1];   // (4096,4096)
    const float* bias = (const float*)d_in[2];   // (1,4096)
    const float* ss   = (const float*)d_in[3];   // (1,4096)
    float* out = (float*)d_out;

    // workspace layout: qi bf16 [8192*4096] | scales f32 [8192] | Wb bf16 [4096*4096]
    unsigned short* qi = (unsigned short*)d_ws;
    float* scales = (float*)((char*)d_ws + (size_t)T_TOK * K_DIM * 2);
    unsigned short* wb = (unsigned short*)((char*)d_ws + (size_t)T_TOK * K_DIM * 2 + T_TOK * 4);

    // 128 KiB dynamic LDS (> 64 KiB default): raise the cap; unconditional —
    // this exact form passed in r1/r2 (the r3 static-guard is the one untested
    // runtime-interaction delta, reverted after the container failure).
    (void)hipFuncSetAttribute(reinterpret_cast<const void*>(gemm256_kernel),
                              hipFuncAttributeMaxDynamicSharedMemorySize, 131072);

    prep_kernel<<<WCONV_BLOCKS + T_TOK, 256, 0, stream>>>(w, wb, x, ss, qi, scales);
    gemm256_kernel<<<dim3(512), dim3(512), 131072, stream>>>(qi, wb, scales, bias, out);
}

// Round 5
// 462.744 us; speedup vs baseline: 1.3150x; 1.0002x over previous
//
#include <hip/hip_runtime.h>
#include <hip/hip_bf16.h>
#include <stdint.h>

// Problem dims (fixed by reference): x (4,2048,4096) f32, W (4096,4096) f32,
// bias (4096) f32, sparsity_scale (4096) f32. Tokens T = 8192.
#define T_TOK 8192
#define K_DIM 4096
#define N_DIM 4096
#define NT 64            // K_DIM / 64  (K-tiles of BK=64)
#define WCONV_BLOCKS 16384   // (4096*4096)/(256*4)

typedef short bf16x8 __attribute__((ext_vector_type(8)));
typedef float f32x4  __attribute__((ext_vector_type(4)));
typedef __attribute__((address_space(3))) char* ldsptr;

// RTNE f32 -> bf16 (bit manipulation; matches numpy/jax casts for finite vals)
__device__ __forceinline__ unsigned short f2bf(float f) {
    uint32_t u = __float_as_uint(f);
    u += 0x7FFFu + ((u >> 16) & 1u);
    return (unsigned short)(u >> 16);
}

// async global->LDS, 16B per lane. LDS dest must be wave-uniform base + lane*16.
__device__ __forceinline__ void gl16(const unsigned short* g, ldsptr l) {
    __builtin_amdgcn_global_load_lds(
        (const __attribute__((address_space(1))) void*)g,
        (__attribute__((address_space(3))) void*)l, 16, 0, 0);
}

// ---------------- kernel 0+1 fused: W f32->bf16  ||  2:4 sparsify + quant ----------
// blocks [0, WCONV_BLOCKS): weight convert; blocks [WCONV_BLOCKS, +T_TOK): sparsequant.
__global__ __launch_bounds__(256) void prep_kernel(
        const float* __restrict__ w, unsigned short* __restrict__ wb,
        const float* __restrict__ x, const float* __restrict__ ss,
        unsigned short* __restrict__ qi, float* __restrict__ scales) {
    const int t = threadIdx.x;
    if (blockIdx.x < WCONV_BLOCKS) {
        int i = (blockIdx.x * 256 + t) * 4;   // 4 floats per thread
        float4 v = *(const float4*)(w + i);
        ushort4 o;
        o.x = f2bf(v.x); o.y = f2bf(v.y); o.z = f2bf(v.z); o.w = f2bf(v.w);
        *(ushort4*)(wb + i) = o;
        return;
    }
    const int row = blockIdx.x - WCONV_BLOCKS;
    const float* xr = x + (size_t)row * K_DIM;

    float xs[16];
    float amax = 0.f;
#pragma unroll
    for (int j = 0; j < 4; ++j) {
        int g = t + 256 * j;                     // group index 0..1023
        float4 v  = ((const float4*)xr)[g];
        float4 sv = ((const float4*)ss)[g];
        float e[4] = { v.x, v.y, v.z, v.w };
        float m[4] = { fabsf(v.x) * sv.x, fabsf(v.y) * sv.y,
                       fabsf(v.z) * sv.z, fabsf(v.w) * sv.w };
#pragma unroll
        for (int a = 0; a < 4; ++a) {
            int cnt = 0;
#pragma unroll
            for (int b = 0; b < 4; ++b) {
                if (b == a) continue;
                // strict-order key (metric, index): matches stable top_k of smallest
                bool less = (m[b] < m[a]) || (m[b] == m[a] && b < a);
                cnt += less ? 1 : 0;
            }
            float kept = (cnt >= 2) ? e[a] : 0.f;   // zero the 2 smallest
            xs[j * 4 + a] = kept;
            amax = fmaxf(amax, fabsf(kept));
        }
    }
#pragma unroll
    for (int off = 32; off >= 1; off >>= 1)
        amax = fmaxf(amax, __shfl_xor(amax, off, 64));
    __shared__ float wm[4];
    int wave = t >> 6, lane = t & 63;
    if (lane == 0) wm[wave] = amax;
    __syncthreads();
    amax = fmaxf(fmaxf(wm[0], wm[1]), fmaxf(wm[2], wm[3]));

    float s = fmaxf(amax, 1e-5f) / 127.0f;   // same f32 ops as reference
    if (t == 0) scales[row] = s;

    unsigned short* qr = qi + (size_t)row * K_DIM;
#pragma unroll
    for (int j = 0; j < 4; ++j) {
        int g = t + 256 * j;
        ushort4 o;
        o.x = f2bf(rintf(xs[j * 4 + 0] / s));    // RTNE div+round, ints exact in bf16
        o.y = f2bf(rintf(xs[j * 4 + 1] / s));
        o.z = f2bf(rintf(xs[j * 4 + 2] / s));
        o.w = f2bf(rintf(xs[j * 4 + 3] / s));
        ((ushort4*)qr)[g] = o;
    }
}

// ---------------- kernel 2: 256x256 pipelined-lgkm GEMM, cluster-interleaved -------
// C[m,n] = scales[m] * sum_k A[m,k]*B[n,k] + bias[n]
// Geometry/LDS/swizzle as r1; staging/vmcnt/barrier skeleton as r2 (proven).
// r5 delta: the WAR-blocked ds_reads (af-h1 in p2, next-tile PF in p4) are issued
// MID-CLUSTER: after the s=0 MFMA half, the [*][0] frag regs are dead -> redefine
// immediately. Gains ~100-300cy issue->wait slack per site at zero extra VGPR.
// lgkm ledger (in-order DS queue, per wave):
//  p1 entry: 12 PF outstanding; +4 bf1; WAIT(4) -> PF retired, bf1 flying
//  p2 WAIT(0) -> bf1 retired; cluster interleaves af-h1 (4 mid + 4 end)
//  p3 WAIT(0) -> af-h1 retired
//  p4 no wait (af-h1 @p3, bf0 @p1); cluster interleaves PF (2 mid + 10 end)
// vmcnt ledger identical to r2 (stages at p1..p4; vm(6) end-p3, vm(4) end-p4;
// edge tiles drain 4->0). Slot-overwrite ledger unchanged (read positions moved
// only WITHIN their original phases).

#define LREAD(dst, base, imm) \
    asm volatile("ds_read_b128 %0, %1 offset:%2" : "=v"(dst) : "v"(base), "i"(imm))

#define WAIT_LGKM(N) do {                                           \
    asm volatile("s_waitcnt lgkmcnt(%0)" :: "i"(N) : "memory");     \
    __builtin_amdgcn_sched_barrier(0);  /* rule #18 */              \
} while (0)

#define WAIT_VM(N) asm volatile("s_waitcnt vmcnt(%0)" :: "i"(N) : "memory")
#define BAR() __builtin_amdgcn_s_barrier()
#define PRIO1 __builtin_amdgcn_s_setprio(1)
#define PRIO0 __builtin_amdgcn_s_setprio(0)
#define NOP do {} while (0)

#define STAGE_A(T, H, BUF) do {                                                  \
    const unsigned short* g_ = pa + (size_t)(H) * 128 * K_DIM + (size_t)(T) * 64;\
    gl16(g_,                      smem3 + ((BUF) * 32768 + (H) * 16384) + tid * 16);          \
    gl16(g_ + (size_t)64 * K_DIM, smem3 + ((BUF) * 32768 + (H) * 16384 + 8192) + tid * 16);   \
} while (0)

#define STAGE_B(T, H, BUF) do {                                                  \
    const unsigned short* g_ = pb + (size_t)(H) * 128 * K_DIM + (size_t)(T) * 64;\
    gl16(g_,                      smem3 + (65536 + (BUF) * 32768 + (H) * 16384) + tid * 16);        \
    gl16(g_ + (size_t)64 * K_DIM, smem3 + (65536 + (BUF) * 32768 + (H) * 16384 + 8192) + tid * 16); \
} while (0)

// 4 reads into af[i][S] (A-half H of BUF, k-subtile S)
#define READ_AF_S(BUF, H, S) do {                                                \
    _Pragma("unroll")                                                            \
    for (int i_ = 0; i_ < 4; ++i_)                                               \
        LREAD(af[i_][S], aB, (BUF) * 32768 + (H) * 16384 + (i_ * 2 + (S)) * 1024);\
} while (0)

// 2 reads into ARR[j][S] (B-half H of BUF, k-subtile S)
#define READ_BF_S(ARR, BUF, H, S) do {                                           \
    _Pragma("unroll")                                                            \
    for (int j_ = 0; j_ < 2; ++j_)                                               \
        LREAD(ARR[j_][S], bB, (BUF) * 32768 + (H) * 16384 + (j_ * 2 + (S)) * 1024);\
} while (0)

// one 8-MFMA half-cluster: quadrant (HA,HB), k-subtile S
#define MFMA_HALF(HA, HB, BF, S) do {                                            \
    _Pragma("unroll")                                                            \
    for (int i_ = 0; i_ < 4; ++i_)                                               \
      _Pragma("unroll")                                                          \
      for (int j_ = 0; j_ < 2; ++j_)                                             \
        acc[HA][i_][HB][j_] = __builtin_amdgcn_mfma_f32_16x16x32_bf16(           \
            af[i_][S], BF[j_][S], acc[HA][i_][HB][j_], 0, 0, 0);                 \
} while (0)

#define TILE(BUF, S1, S2, S3, S4, PFI, W3, W4) do {                              \
    /* p1: (0,0) on af-h0/bf0 (PF'd in prev p4) */                               \
    READ_BF_S(bf1, BUF, 1, 0); READ_BF_S(bf1, BUF, 1, 1);                        \
    S1;                                                                          \
    WAIT_LGKM(4);                                                                \
    PRIO1; MFMA_HALF(0, 0, bf0, 0); MFMA_HALF(0, 0, bf0, 1); PRIO0;              \
    BAR();                                                                       \
    /* p2: (0,1); af-h1 reads interleaved mid/end-cluster (af[*][S] dead after   \
       its s=S half) */                                                          \
    S2;                                                                          \
    WAIT_LGKM(0);                                                                \
    PRIO1; MFMA_HALF(0, 1, bf1, 0);                                              \
    READ_AF_S(BUF, 1, 0);                                                        \
    MFMA_HALF(0, 1, bf1, 1); PRIO0;                                              \
    READ_AF_S(BUF, 1, 1);                                                        \
    BAR();                                                                       \
    /* p3: (1,1) */                                                              \
    S3;                                                                          \
    WAIT_LGKM(0);                                                                \
    PRIO1; MFMA_HALF(1, 1, bf1, 0); MFMA_HALF(1, 1, bf1, 1); PRIO0;              \
    W3;                                                                          \
    BAR();                                                                       \
    /* p4: (1,0); next-tile PF interleaved (bf0[*][0] dead after s0 half) */     \
    S4;                                                                          \
    PRIO1; MFMA_HALF(1, 0, bf0, 0);                                              \
    if (PFI) { READ_BF_S(bf0, (BUF) ^ 1, 0, 0); }                                \
    MFMA_HALF(1, 0, bf0, 1); PRIO0;                                              \
    if (PFI) { READ_BF_S(bf0, (BUF) ^ 1, 0, 1);                                  \
               READ_AF_S((BUF) ^ 1, 0, 0); READ_AF_S((BUF) ^ 1, 0, 1); }         \
    W4;                                                                          \
    BAR();                                                                       \
} while (0)

__global__ __launch_bounds__(512, 2) void gemm256_kernel(
        const unsigned short* __restrict__ A,     // [M,K] bf16 (qi)
        const unsigned short* __restrict__ B,     // [N,K] bf16 (Wb)
        const float* __restrict__ scales,         // [M]
        const float* __restrict__ bias,           // [N]
        float* __restrict__ C) {                  // [M,N] f32
    extern __shared__ char smem[];
    ldsptr smem3 = (ldsptr)smem;

    const int tid = threadIdx.x;

    // 2D-chunked bijective XCD swizzle (r4-proven): 8 XCDs as 4x2 chunks of 8x8
    // tiles -> per-XCD L2 sees 16MB A + 16MB B. FETCH measured 197MB.
    const int wg   = blockIdx.x;
    const int xcd  = wg & 7;
    const int idx  = wg >> 3;                 // 0..63 within chunk
    const int tm   = (xcd >> 1) * 8 + (idx & 7);    // 0..31
    const int tn   = (xcd & 1) * 8 + (idx >> 3);    // 0..15
    const int tmBase = tm * 256, tnBase = tn * 256;

    // staging source decomposition (pre-swizzled global source, linear LDS dest)
    const int st0  = tid >> 6;                          // subtile id within call 0
    const int r16s = (tid >> 2) & 15;
    const int q4   = tid & 3;
    const int r0   = ((st0 >> 1) << 4) + r16s;          // 0..63 (call1: +64)
    const int kk0  = ((st0 & 1) << 5) + ((q4 * 8) ^ ((r16s >> 3) << 4));
    const unsigned short* pa = A + (size_t)(tmBase + r0) * K_DIM + kk0;
    const unsigned short* pb = B + (size_t)(tnBase + r0) * K_DIM + kk0;

    // ds_read lane bases (loop-invariant; swizzle XOR folded in once)
    const int lane = tid & 63, wave = tid >> 6;
    const int wr = wave >> 2, wc = wave & 3;            // 2M x 4N waves
    const int laneoff = (lane & 15) * 64 +
        ((((lane >> 4) * 8) ^ (((lane >> 3) & 1) << 4)) << 1);
    ldsptr aB = smem3 + wr * 8192 + laneoff;
    ldsptr bB = smem3 + 65536 + wc * 4096 + laneoff;

    bf16x8 af[4][2], bf0[2][2], bf1[2][2];
    f32x4 acc[2][4][2][2];
    const f32x4 z = { 0.f, 0.f, 0.f, 0.f };
#pragma unroll
    for (int a0 = 0; a0 < 2; ++a0)
#pragma unroll
      for (int a1 = 0; a1 < 4; ++a1)
#pragma unroll
        for (int a2 = 0; a2 < 2; ++a2)
#pragma unroll
          for (int a3 = 0; a3 < 2; ++a3) acc[a0][a1][a2][a3] = z;

    // prologue: stage tile0 (A0,B0,A1,B1)->buf0, tile1 (A0,B0)->buf1.
    // vmcnt(4): first 4 half-tiles landed, A0(1)/B0(1) in flight.
    STAGE_A(0, 0, 0); STAGE_B(0, 0, 0); STAGE_A(0, 1, 0); STAGE_B(0, 1, 0);
    STAGE_A(1, 0, 1); STAGE_B(1, 0, 1);
    WAIT_VM(4);
    BAR();
    READ_AF_S(0, 0, 0); READ_AF_S(0, 0, 1);      // af-h0(0): 8 reads
    READ_BF_S(bf0, 0, 0, 0); READ_BF_S(bf0, 0, 0, 1);  // bf0(0): 4 reads

    // steady tiles 0..61 (pairs: buf 0 then buf 1)
    for (int t = 0; t < NT - 2; t += 2) {
        TILE(0, STAGE_A(t + 1, 1, 1), STAGE_B(t + 1, 1, 1),
                STAGE_A(t + 2, 0, 0), STAGE_B(t + 2, 0, 0),
                1, WAIT_VM(6), WAIT_VM(4));
        TILE(1, STAGE_A(t + 2, 1, 0), STAGE_B(t + 2, 1, 0),
                STAGE_A(t + 3, 0, 1), STAGE_B(t + 3, 0, 1),
                1, WAIT_VM(6), WAIT_VM(4));
    }
    // tile 62 (buf 0): only A1/B1(63) remain to stage; drain vmcnt by the end.
    TILE(0, STAGE_A(63, 1, 1), STAGE_B(63, 1, 1), NOP, NOP,
            1, WAIT_VM(4), WAIT_VM(0));
    // tile 63 (buf 1): nothing to stage or prefetch beyond.
    TILE(1, NOP, NOP, NOP, NOP, 0, NOP, NOP);

    // epilogue: D row = (lane>>4)*4+reg (A side), col = lane&15 (B side)
#pragma unroll
    for (int ha = 0; ha < 2; ++ha)
#pragma unroll
      for (int i = 0; i < 4; ++i) {
        const int rbase = tmBase + ha * 128 + wr * 64 + i * 16 + (lane >> 4) * 4;
        float sc[4];
#pragma unroll
        for (int r = 0; r < 4; ++r) sc[r] = scales[rbase + r];
#pragma unroll
        for (int hb = 0; hb < 2; ++hb)
#pragma unroll
          for (int j = 0; j < 2; ++j) {
            const int col = tnBase + hb * 128 + wc * 32 + j * 16 + (lane & 15);
            const float bb = bias[col];
#pragma unroll
            for (int r = 0; r < 4; ++r)
                C[(size_t)(rbase + r) * N_DIM + col] = sc[r] * acc[ha][i][hb][j][r] + bb;
          }
      }
}

extern "C" void kernel_launch(void* const* d_in, const int* in_sizes, int n_in,
                              void* d_out, int out_size, void* d_ws, size_t ws_size,
                              hipStream_t stream) {
    const float* x    = (const float*)d_in[0];   // (4,2048,4096)
    const float* w    = (const float*)d_in[1];   // (4096,4096)
    const float* bias = (const float*)d_in[2];   // (1,4096)
    const float* ss   = (const float*)d_in[3];   // (1,4096)
    float* out = (float*)d_out;

    // workspace layout: qi bf16 [8192*4096] | scales f32 [8192] | Wb bf16 [4096*4096]
    unsigned short* qi = (unsigned short*)d_ws;
    float* scales = (float*)((char*)d_ws + (size_t)T_TOK * K_DIM * 2);
    unsigned short* wb = (unsigned short*)((char*)d_ws + (size_t)T_TOK * K_DIM * 2 + T_TOK * 4);

    // 128 KiB dynamic LDS: raise the cap (unconditional — r1/r2/r4-proven form).
    (void)hipFuncSetAttribute(reinterpret_cast<const void*>(gemm256_kernel),
                              hipFuncAttributeMaxDynamicSharedMemorySize, 131072);

    prep_kernel<<<WCONV_BLOCKS + T_TOK, 256, 0, stream>>>(w, wb, x, ss, qi, scales);
    gemm256_kernel<<<dim3(512), dim3(512), 131072, stream>>>(qi, wb, scales, bias, out);
}